// Round 1
// baseline (8898.656 us; speedup 1.0000x reference)
//
#include <hip/hip_runtime.h>
#include <math.h>

#define N_NODES   50000
#define N_EDGES   800000
#define BASIS     64
#define HIDDEN_RO 128
#define N_GRAPHS  512
#define T_ITERS   3

// tanh via exp, overflow-safe: tanh(x) = sign(x) * (1 - e^{-2|x|}) / (1 + e^{-2|x|})
__device__ __forceinline__ float fast_tanh(float x) {
    float a = fabsf(x);
    float t = __expf(-2.0f * a);
    float r = (1.0f - t) / (1.0f + t);
    return copysignf(r, x);
}

// C[n, :] = embed[Z[n], :]
__global__ void k_init_C(const int* __restrict__ Z, const float* __restrict__ embed,
                         float* __restrict__ C) {
    int i = blockIdx.x * blockDim.x + threadIdx.x;
    if (i >= N_NODES * BASIS) return;
    int n = i >> 6, c = i & 63;
    C[i] = embed[Z[n] * BASIS + c];
}

// out[r, :] = in[r, :] @ W(64x64) + b   (thread per row, acc[64] in VGPRs, W via scalar loads)
__global__ void k_rows_linear64(const float* __restrict__ in, const float* __restrict__ W,
                                const float* __restrict__ b, float* __restrict__ out, int rows) {
    int r = blockIdx.x * blockDim.x + threadIdx.x;
    if (r >= rows) return;
    float acc[BASIS];
    #pragma unroll
    for (int c = 0; c < BASIS; ++c) acc[c] = b[c];
    const float4* in4 = (const float4*)(in + (size_t)r * BASIS);
    #pragma unroll 1
    for (int k0 = 0; k0 < BASIS / 4; ++k0) {
        float4 xv = in4[k0];
        const float* w0 = W + (k0 * 4 + 0) * BASIS;
        const float* w1 = W + (k0 * 4 + 1) * BASIS;
        const float* w2 = W + (k0 * 4 + 2) * BASIS;
        const float* w3 = W + (k0 * 4 + 3) * BASIS;
        #pragma unroll
        for (int c = 0; c < BASIS; ++c) acc[c] += xv.x * w0[c];
        #pragma unroll
        for (int c = 0; c < BASIS; ++c) acc[c] += xv.y * w1[c];
        #pragma unroll
        for (int c = 0; c < BASIS; ++c) acc[c] += xv.z * w2[c];
        #pragma unroll
        for (int c = 0; c < BASIS; ++c) acc[c] += xv.w * w3[c];
    }
    float4* out4 = (float4*)(out + (size_t)r * BASIS);
    #pragma unroll
    for (int c0 = 0; c0 < BASIS / 4; ++c0)
        out4[c0] = make_float4(acc[4 * c0], acc[4 * c0 + 1], acc[4 * c0 + 2], acc[4 * c0 + 3]);
}

// Per edge: x = CF[src] * d_feat ; m = tanh(x @ fcW) ; atomicAdd(C[dst], m)
// HAS_DF: d_feat precomputed in DF.  !HAS_DF: recompute d_feat = ea@dfW+dfb inline (ws fallback).
template <bool HAS_DF>
__global__ void k_edge(const float* __restrict__ CF, const float* __restrict__ DF,
                       const float* __restrict__ ea, const float* __restrict__ dfW,
                       const float* __restrict__ dfb, const float* __restrict__ fcW,
                       const int* __restrict__ src, const int* __restrict__ dst,
                       float* __restrict__ C) {
    int e = blockIdx.x * blockDim.x + threadIdx.x;
    if (e >= N_EDGES) return;
    int s = src[e], d = dst[e];
    const float4* cf4 = (const float4*)(CF + (size_t)s * BASIS);

    float acc[BASIS];
    #pragma unroll
    for (int c = 0; c < BASIS; ++c) acc[c] = 0.0f;

    if (HAS_DF) {
        const float4* df4 = (const float4*)(DF + (size_t)e * BASIS);
        #pragma unroll 1
        for (int k0 = 0; k0 < BASIS / 4; ++k0) {
            float4 a = cf4[k0];
            float4 bb = df4[k0];
            float xs0 = a.x * bb.x, xs1 = a.y * bb.y, xs2 = a.z * bb.z, xs3 = a.w * bb.w;
            const float* w0 = fcW + (k0 * 4 + 0) * BASIS;
            const float* w1 = fcW + (k0 * 4 + 1) * BASIS;
            const float* w2 = fcW + (k0 * 4 + 2) * BASIS;
            const float* w3 = fcW + (k0 * 4 + 3) * BASIS;
            #pragma unroll
            for (int c = 0; c < BASIS; ++c) acc[c] += xs0 * w0[c];
            #pragma unroll
            for (int c = 0; c < BASIS; ++c) acc[c] += xs1 * w1[c];
            #pragma unroll
            for (int c = 0; c < BASIS; ++c) acc[c] += xs2 * w2[c];
            #pragma unroll
            for (int c = 0; c < BASIS; ++c) acc[c] += xs3 * w3[c];
        }
    } else {
        // d_feat = ea[e,:] @ dfW + dfb
        float dfeat[BASIS];
        #pragma unroll
        for (int c = 0; c < BASIS; ++c) dfeat[c] = dfb[c];
        const float4* ea4 = (const float4*)(ea + (size_t)e * BASIS);
        #pragma unroll 1
        for (int k0 = 0; k0 < BASIS / 4; ++k0) {
            float4 xv = ea4[k0];
            const float* w0 = dfW + (k0 * 4 + 0) * BASIS;
            const float* w1 = dfW + (k0 * 4 + 1) * BASIS;
            const float* w2 = dfW + (k0 * 4 + 2) * BASIS;
            const float* w3 = dfW + (k0 * 4 + 3) * BASIS;
            #pragma unroll
            for (int c = 0; c < BASIS; ++c) dfeat[c] += xv.x * w0[c];
            #pragma unroll
            for (int c = 0; c < BASIS; ++c) dfeat[c] += xv.y * w1[c];
            #pragma unroll
            for (int c = 0; c < BASIS; ++c) dfeat[c] += xv.z * w2[c];
            #pragma unroll
            for (int c = 0; c < BASIS; ++c) dfeat[c] += xv.w * w3[c];
        }
        #pragma unroll   // full unroll: dfeat indices must stay constant
        for (int k0 = 0; k0 < BASIS / 4; ++k0) {
            float4 a = cf4[k0];
            float xs0 = a.x * dfeat[4 * k0 + 0];
            float xs1 = a.y * dfeat[4 * k0 + 1];
            float xs2 = a.z * dfeat[4 * k0 + 2];
            float xs3 = a.w * dfeat[4 * k0 + 3];
            const float* w0 = fcW + (k0 * 4 + 0) * BASIS;
            const float* w1 = fcW + (k0 * 4 + 1) * BASIS;
            const float* w2 = fcW + (k0 * 4 + 2) * BASIS;
            const float* w3 = fcW + (k0 * 4 + 3) * BASIS;
            #pragma unroll
            for (int c = 0; c < BASIS; ++c) acc[c] += xs0 * w0[c];
            #pragma unroll
            for (int c = 0; c < BASIS; ++c) acc[c] += xs1 * w1[c];
            #pragma unroll
            for (int c = 0; c < BASIS; ++c) acc[c] += xs2 * w2[c];
            #pragma unroll
            for (int c = 0; c < BASIS; ++c) acc[c] += xs3 * w3[c];
        }
    }

    float* crow = C + (size_t)d * BASIS;
    #pragma unroll
    for (int c = 0; c < BASIS; ++c) {
        float m = fast_tanh(acc[c]);
        atomicAdd(&crow[c], m);
    }
}

// h = tanh(C@W1+b1) @ W2 + b2 ; atomicAdd into out[batch[n], :]
__global__ void k_readout(const float* __restrict__ C, const float* __restrict__ W1,
                          const float* __restrict__ b1, const float* __restrict__ W2,
                          const float* __restrict__ b2, const int* __restrict__ batch,
                          float* __restrict__ out) {
    int n = blockIdx.x * blockDim.x + threadIdx.x;
    if (n >= N_NODES) return;
    const float4* c4 = (const float4*)(C + (size_t)n * BASIS);
    float o0 = b2[0], o1 = b2[1], o2 = b2[2], o3 = b2[3];

    #pragma unroll 1
    for (int half = 0; half < 2; ++half) {
        float acc[64];
        #pragma unroll
        for (int j = 0; j < 64; ++j) acc[j] = b1[half * 64 + j];
        #pragma unroll 1
        for (int k0 = 0; k0 < BASIS / 4; ++k0) {
            float4 xv = c4[k0];   // re-read; L1-hot on second half pass
            const float* w0 = W1 + (k0 * 4 + 0) * HIDDEN_RO + half * 64;
            const float* w1 = W1 + (k0 * 4 + 1) * HIDDEN_RO + half * 64;
            const float* w2 = W1 + (k0 * 4 + 2) * HIDDEN_RO + half * 64;
            const float* w3 = W1 + (k0 * 4 + 3) * HIDDEN_RO + half * 64;
            #pragma unroll
            for (int j = 0; j < 64; ++j) acc[j] += xv.x * w0[j];
            #pragma unroll
            for (int j = 0; j < 64; ++j) acc[j] += xv.y * w1[j];
            #pragma unroll
            for (int j = 0; j < 64; ++j) acc[j] += xv.z * w2[j];
            #pragma unroll
            for (int j = 0; j < 64; ++j) acc[j] += xv.w * w3[j];
        }
        #pragma unroll
        for (int j = 0; j < 64; ++j) {
            float h = fast_tanh(acc[j]);
            const float* w2r = W2 + (size_t)(half * 64 + j) * 4;
            o0 += h * w2r[0];
            o1 += h * w2r[1];
            o2 += h * w2r[2];
            o3 += h * w2r[3];
        }
    }
    int g = batch[n];
    float* og = out + (size_t)g * 4;
    atomicAdd(&og[0], o0);
    atomicAdd(&og[1], o1);
    atomicAdd(&og[2], o2);
    atomicAdd(&og[3], o3);
}

extern "C" void kernel_launch(void* const* d_in, const int* in_sizes, int n_in,
                              void* d_out, int out_size, void* d_ws, size_t ws_size,
                              hipStream_t stream) {
    // Input order: Z, edge_index, edge_attr, batch, embed, cfW, cfb, dfW, dfb, fcW, W1, b1, W2, b2
    const int*   Z     = (const int*)d_in[0];
    const int*   ei    = (const int*)d_in[1];
    const float* ea    = (const float*)d_in[2];
    const int*   batch = (const int*)d_in[3];
    const float* embed = (const float*)d_in[4];
    const float* cfW   = (const float*)d_in[5];
    const float* cfb   = (const float*)d_in[6];
    const float* dfW   = (const float*)d_in[7];
    const float* dfb   = (const float*)d_in[8];
    const float* fcW   = (const float*)d_in[9];
    const float* W1    = (const float*)d_in[10];
    const float* b1    = (const float*)d_in[11];
    const float* W2    = (const float*)d_in[12];
    const float* b2    = (const float*)d_in[13];
    const int* src = ei;             // edge_index[0, :]
    const int* dst = ei + N_EDGES;   // edge_index[1, :]
    float* out = (float*)d_out;

    const size_t bytesC  = (size_t)N_NODES * BASIS * sizeof(float);   // 12.8 MB
    const size_t bytesDF = (size_t)N_EDGES * BASIS * sizeof(float);   // 204.8 MB
    char* p = (char*)d_ws;
    float* C  = (float*)p;              p += bytesC;
    float* CF = (float*)p;              p += bytesC;
    const bool has_df = ws_size >= 2 * bytesC + bytesDF;
    float* DF = has_df ? (float*)p : nullptr;

    hipMemsetAsync(d_out, 0, (size_t)out_size * sizeof(float), stream);

    k_init_C<<<(N_NODES * BASIS + 255) / 256, 256, 0, stream>>>(Z, embed, C);

    if (has_df) {
        k_rows_linear64<<<(N_EDGES + 255) / 256, 256, 0, stream>>>(ea, dfW, dfb, DF, N_EDGES);
    }

    for (int t = 0; t < T_ITERS; ++t) {
        // CF = C @ cfW + cfb  (node-level: (C@W)[src] == (C[src])@W, 16x fewer FLOPs)
        k_rows_linear64<<<(N_NODES + 255) / 256, 256, 0, stream>>>(C, cfW, cfb, CF, N_NODES);
        if (has_df) {
            k_edge<true><<<(N_EDGES + 255) / 256, 256, 0, stream>>>(
                CF, DF, nullptr, nullptr, nullptr, fcW, src, dst, C);
        } else {
            k_edge<false><<<(N_EDGES + 255) / 256, 256, 0, stream>>>(
                CF, nullptr, ea, dfW, dfb, fcW, src, dst, C);
        }
    }

    k_readout<<<(N_NODES + 255) / 256, 256, 0, stream>>>(C, W1, b1, W2, b2, batch, out);
}

// Round 2
// 1807.856 us; speedup vs baseline: 4.9222x; 4.9222x over previous
//
#include <hip/hip_runtime.h>
#include <math.h>

#define N_NODES   50000
#define N_EDGES   800000
#define BASIS     64
#define HIDDEN_RO 128
#define N_GRAPHS  512
#define T_ITERS   3

// tanh via exp, overflow-safe: tanh(x) = sign(x)*(1-e^{-2|x|})/(1+e^{-2|x|})
__device__ __forceinline__ float fast_tanh(float x) {
    float a = fabsf(x);
    float t = __expf(-2.0f * a);
    float r = (1.0f - t) / (1.0f + t);
    return copysignf(r, x);
}

// C[n,:] = embed[Z[n],:]
__global__ void k_init_C(const int* __restrict__ Z, const float* __restrict__ embed,
                         float* __restrict__ C) {
    int i = blockIdx.x * blockDim.x + threadIdx.x;
    if (i >= N_NODES * BASIS) return;
    int n = i >> 6, c = i & 63;
    C[i] = embed[Z[n] * BASIS + c];
}

// ---- wave-per-row linear: out[r,:] = in[r,:] @ W(64x64) + b ----
// lane c holds W column c in 64 VGPRs; x row staged in LDS, read back as
// lane-uniform ds_read_b128 broadcasts (conflict-free).
__global__ __launch_bounds__(256) void k_linear64(const float* __restrict__ in,
        const float* __restrict__ W, const float* __restrict__ b,
        float* __restrict__ out, int rows) {
    __shared__ float xbuf[4][64];
    int lane = threadIdx.x & 63;
    int wv   = threadIdx.x >> 6;
    float w[64];
    #pragma unroll
    for (int k = 0; k < 64; ++k) w[k] = W[k * 64 + lane];  // coalesced per k
    float bias = b[lane];
    int wave = blockIdx.x * 4 + wv;
    int nw   = gridDim.x * 4;
    for (int r = wave; r < rows; r += nw) {
        float x = in[(size_t)r * 64 + lane];
        xbuf[wv][lane] = x;
        __builtin_amdgcn_wave_barrier();   // same-wave LDS ops are in-order; pin compiler order
        const float4* xb = (const float4*)xbuf[wv];
        float sum = bias;
        #pragma unroll
        for (int k4 = 0; k4 < 16; ++k4) {
            float4 xv = xb[k4];            // lane-uniform address -> broadcast
            sum += xv.x * w[4*k4+0] + xv.y * w[4*k4+1]
                 + xv.z * w[4*k4+2] + xv.w * w[4*k4+3];
        }
        out[(size_t)r * 64 + lane] = sum;
        __builtin_amdgcn_wave_barrier();
    }
}

// ---- CSR build ----
__global__ void k_hist(const int* __restrict__ dst, int* __restrict__ deg) {
    int e = blockIdx.x * blockDim.x + threadIdx.x;
    if (e < N_EDGES) atomicAdd(&deg[dst[e]], 1);
}

// single-block exclusive scan over 50k counts -> off[0..N], cursor copy
__global__ void k_scan(const int* __restrict__ deg, int* __restrict__ off,
                       int* __restrict__ cursor) {
    __shared__ int lds[1024];
    __shared__ int s_run;
    int t = threadIdx.x;
    if (t == 0) s_run = 0;
    __syncthreads();
    for (int base = 0; base < N_NODES; base += 1024) {
        int i = base + t;
        int v = (i < N_NODES) ? deg[i] : 0;
        lds[t] = v;
        __syncthreads();
        for (int ofs = 1; ofs < 1024; ofs <<= 1) {   // Hillis-Steele inclusive
            int tmp = (t >= ofs) ? lds[t - ofs] : 0;
            __syncthreads();
            lds[t] += tmp;
            __syncthreads();
        }
        int incl = lds[t];
        int run = s_run;
        __syncthreads();
        if (i < N_NODES) { int o = run + incl - v; off[i] = o; cursor[i] = o; }
        if (t == 1023) s_run = run + incl;           // chunk total
        __syncthreads();
    }
    if (t == 0) off[N_NODES] = s_run;
}

__global__ void k_fill(const int* __restrict__ dst, int* __restrict__ cursor,
                       int* __restrict__ eid) {
    int e = blockIdx.x * blockDim.x + threadIdx.x;
    if (e < N_EDGES) {
        int p = atomicAdd(&cursor[dst[e]], 1);
        eid[p] = e;
    }
}

// ---- fused message+aggregate: wave per node, lane = channel ----
// acc_c = sum_{e in in(n)} tanh( sum_k (CF[src_e,k]*DF[e,k]) * fcW[k,c] )
// C[n,c] += acc_c.  No float atomics.
template <bool HAS_DF>
__global__ __launch_bounds__(256) void k_mp(const float* __restrict__ CF,
        const float* __restrict__ DF, const float* __restrict__ ea,
        const float* __restrict__ dfW, const float* __restrict__ dfb,
        const float* __restrict__ fcW, const int* __restrict__ src,
        const int* __restrict__ off, const int* __restrict__ eid,
        float* __restrict__ C) {
    __shared__ float xbuf[4][64];
    __shared__ float abuf[4][64];
    int lane = threadIdx.x & 63;
    int wv   = threadIdx.x >> 6;
    float w[64];
    #pragma unroll
    for (int k = 0; k < 64; ++k) w[k] = fcW[k * 64 + lane];
    float wd0 = 0.0f; float wd[64]; float dbias = 0.0f;
    if constexpr (!HAS_DF) {
        #pragma unroll
        for (int k = 0; k < 64; ++k) wd[k] = dfW[k * 64 + lane];
        dbias = dfb[lane];
    }
    (void)wd0;
    int wave = blockIdx.x * 4 + wv;
    int nw   = gridDim.x * 4;
    for (int n = wave; n < N_NODES; n += nw) {
        int beg = off[n], end = off[n + 1];
        float acc = 0.0f;
        for (int idx = beg; idx < end; ++idx) {
            int e = eid[idx];
            int s = src[e];
            float d;
            if constexpr (HAS_DF) {
                d = DF[(size_t)e * 64 + lane];
            } else {
                abuf[wv][lane] = ea[(size_t)e * 64 + lane];
                __builtin_amdgcn_wave_barrier();
                const float4* ab = (const float4*)abuf[wv];
                d = dbias;
                #pragma unroll
                for (int k4 = 0; k4 < 16; ++k4) {
                    float4 av = ab[k4];
                    d += av.x * wd[4*k4+0] + av.y * wd[4*k4+1]
                       + av.z * wd[4*k4+2] + av.w * wd[4*k4+3];
                }
                __builtin_amdgcn_wave_barrier();
            }
            float x = CF[(size_t)s * 64 + lane] * d;
            xbuf[wv][lane] = x;
            __builtin_amdgcn_wave_barrier();
            const float4* xb = (const float4*)xbuf[wv];
            float sum = 0.0f;
            #pragma unroll
            for (int k4 = 0; k4 < 16; ++k4) {
                float4 xv = xb[k4];
                sum += xv.x * w[4*k4+0] + xv.y * w[4*k4+1]
                     + xv.z * w[4*k4+2] + xv.w * w[4*k4+3];
            }
            acc += fast_tanh(sum);
            __builtin_amdgcn_wave_barrier();
        }
        size_t ci = (size_t)n * 64 + lane;
        C[ci] += acc;                     // only this wave owns node n
    }
}

// ---- readout: wave per node, W1 staged in LDS (32 KB), lane covers 2 hidden ----
__global__ __launch_bounds__(256) void k_readout2(const float* __restrict__ C,
        const float* __restrict__ W1, const float* __restrict__ b1,
        const float* __restrict__ W2, const float* __restrict__ b2,
        const int* __restrict__ batch, float* __restrict__ out) {
    __shared__ float w1[BASIS * HIDDEN_RO];   // 32 KB
    __shared__ float xbuf[4][64];
    int t = threadIdx.x;
    for (int i = t; i < BASIS * HIDDEN_RO; i += 256) w1[i] = W1[i];
    __syncthreads();
    int lane = t & 63, wv = t >> 6;
    float b1a = b1[lane], b1b = b1[64 + lane];
    float4 w2a = ((const float4*)W2)[lane];        // W2 row j=lane
    float4 w2b = ((const float4*)W2)[64 + lane];   // W2 row j=64+lane
    int wave = blockIdx.x * 4 + wv;
    int nw   = gridDim.x * 4;
    for (int n = wave; n < N_NODES; n += nw) {
        float x = C[(size_t)n * 64 + lane];
        xbuf[wv][lane] = x;
        __builtin_amdgcn_wave_barrier();
        const float4* xb = (const float4*)xbuf[wv];
        float sa = b1a, sb = b1b;
        #pragma unroll
        for (int k4 = 0; k4 < 16; ++k4) {
            float4 xv = xb[k4];
            const float* r0 = &w1[(4*k4 + 0) * HIDDEN_RO];
            const float* r1 = &w1[(4*k4 + 1) * HIDDEN_RO];
            const float* r2 = &w1[(4*k4 + 2) * HIDDEN_RO];
            const float* r3 = &w1[(4*k4 + 3) * HIDDEN_RO];
            sa += xv.x * r0[lane]      + xv.y * r1[lane]
                + xv.z * r2[lane]      + xv.w * r3[lane];
            sb += xv.x * r0[64 + lane] + xv.y * r1[64 + lane]
                + xv.z * r2[64 + lane] + xv.w * r3[64 + lane];
        }
        float ha = fast_tanh(sa), hb = fast_tanh(sb);
        float v0 = ha * w2a.x + hb * w2b.x;
        float v1 = ha * w2a.y + hb * w2b.y;
        float v2 = ha * w2a.z + hb * w2b.z;
        float v3 = ha * w2a.w + hb * w2b.w;
        #pragma unroll
        for (int ofs = 32; ofs >= 1; ofs >>= 1) {
            v0 += __shfl_down(v0, ofs, 64);
            v1 += __shfl_down(v1, ofs, 64);
            v2 += __shfl_down(v2, ofs, 64);
            v3 += __shfl_down(v3, ofs, 64);
        }
        if (lane == 0) {
            int g = batch[n];
            atomicAdd(&out[(size_t)g * 4 + 0], v0);
            atomicAdd(&out[(size_t)g * 4 + 1], v1);
            atomicAdd(&out[(size_t)g * 4 + 2], v2);
            atomicAdd(&out[(size_t)g * 4 + 3], v3);
        }
        __builtin_amdgcn_wave_barrier();
    }
}

extern "C" void kernel_launch(void* const* d_in, const int* in_sizes, int n_in,
                              void* d_out, int out_size, void* d_ws, size_t ws_size,
                              hipStream_t stream) {
    // Z, edge_index, edge_attr, batch, embed, cfW, cfb, dfW, dfb, fcW, W1, b1, W2, b2
    const int*   Z     = (const int*)d_in[0];
    const int*   ei    = (const int*)d_in[1];
    const float* ea    = (const float*)d_in[2];
    const int*   batch = (const int*)d_in[3];
    const float* embed = (const float*)d_in[4];
    const float* cfW   = (const float*)d_in[5];
    const float* cfb   = (const float*)d_in[6];
    const float* dfW   = (const float*)d_in[7];
    const float* dfb   = (const float*)d_in[8];
    const float* fcW   = (const float*)d_in[9];
    const float* W1    = (const float*)d_in[10];
    const float* b1    = (const float*)d_in[11];
    const float* W2    = (const float*)d_in[12];
    const float* b2    = (const float*)d_in[13];
    const int* src = ei;
    const int* dst = ei + N_EDGES;
    float* out = (float*)d_out;

    const size_t bytesC   = (size_t)N_NODES * BASIS * sizeof(float);   // 12.8 MB
    const size_t bytesDF  = (size_t)N_EDGES * BASIS * sizeof(float);   // 204.8 MB
    const size_t bytesEid = (size_t)N_EDGES * sizeof(int);             // 3.2 MB
    const size_t bytesDeg = (size_t)(N_NODES + 1) * sizeof(int);

    char* p = (char*)d_ws;
    float* C      = (float*)p;  p += bytesC;
    float* CF     = (float*)p;  p += bytesC;
    int*   eid    = (int*)p;    p += bytesEid;
    int*   deg    = (int*)p;    p += bytesDeg;
    int*   off    = (int*)p;    p += bytesDeg;
    int*   cursor = (int*)p;    p += bytesDeg;
    size_t used_mid = (size_t)(p - (char*)d_ws);
    float* DF = (float*)p;
    const bool has_csr = ws_size >= used_mid;
    const bool has_df  = ws_size >= used_mid + bytesDF;

    hipMemsetAsync(d_out, 0, (size_t)out_size * sizeof(float), stream);

    k_init_C<<<(N_NODES * BASIS + 255) / 256, 256, 0, stream>>>(Z, embed, C);

    if (has_csr) {
        hipMemsetAsync(deg, 0, bytesDeg, stream);
        k_hist<<<(N_EDGES + 255) / 256, 256, 0, stream>>>(dst, deg);
        k_scan<<<1, 1024, 0, stream>>>(deg, off, cursor);
        k_fill<<<(N_EDGES + 255) / 256, 256, 0, stream>>>(dst, cursor, eid);

        if (has_df) {
            k_linear64<<<2048, 256, 0, stream>>>(ea, dfW, dfb, DF, N_EDGES);
        }
        for (int t = 0; t < T_ITERS; ++t) {
            k_linear64<<<512, 256, 0, stream>>>(C, cfW, cfb, CF, N_NODES);
            if (has_df) {
                k_mp<true><<<2048, 256, 0, stream>>>(CF, DF, nullptr, nullptr, nullptr,
                                                     fcW, src, off, eid, C);
            } else {
                k_mp<false><<<2048, 256, 0, stream>>>(CF, nullptr, ea, dfW, dfb,
                                                      fcW, src, off, eid, C);
            }
        }
    } else {
        // ultra fallback: should not happen (round-1 proved ws >= 230 MB)
        for (int t = 0; t < T_ITERS; ++t) {
            k_linear64<<<512, 256, 0, stream>>>(C, cfW, cfb, CF, N_NODES);
            // no CSR space: nothing better available; CSR arrays are small, so
            // this branch is effectively unreachable.
        }
    }

    k_readout2<<<512, 256, 0, stream>>>(C, W1, b1, W2, b2, batch, out);
}

// Round 3
// 979.409 us; speedup vs baseline: 9.0857x; 1.8459x over previous
//
#include <hip/hip_runtime.h>
#include <math.h>

#define N_NODES   50000
#define N_EDGES   800000
#define BASIS     64
#define HIDDEN_RO 128
#define N_GRAPHS  512
#define T_ITERS   3

typedef short s8 __attribute__((ext_vector_type(8)));   // 8 bf16 in 4 VGPRs
typedef float f4 __attribute__((ext_vector_type(4)));

#define MFMA16(a, b, c) __builtin_amdgcn_mfma_f32_16x16x32_bf16(a, b, c, 0, 0, 0)

// tanh(x) = 1 - 2/(e^{2x}+1); overflow-safe both directions, tanh(0)=0 exactly.
__device__ __forceinline__ float fast_tanh(float x) {
    float e = __expf(2.0f * x);
    return 1.0f - 2.0f / (e + 1.0f);
}

__device__ __forceinline__ f4 splat4(float x) { f4 v; v[0]=x; v[1]=x; v[2]=x; v[3]=x; return v; }

// Split 8 fp32 into bf16 hi (truncation) + bf16 lo (exact residual's top bits).
// x = hi + lo + O(2^-16 x): hi@Whi + hi@Wlo + lo@Whi recovers ~fp32 accuracy.
__device__ __forceinline__ void split8(const float* x, s8& hi, s8& lo) {
    union { unsigned a[4]; s8 v; } H, L;
    #pragma unroll
    for (int j = 0; j < 4; ++j) {
        float e0 = x[2*j], e1 = x[2*j+1];
        unsigned u0 = __float_as_uint(e0), u1 = __float_as_uint(e1);
        H.a[j] = (u0 >> 16) | (u1 & 0xFFFF0000u);
        float l0 = e0 - __uint_as_float(u0 & 0xFFFF0000u);   // exact
        float l1 = e1 - __uint_as_float(u1 & 0xFFFF0000u);
        L.a[j] = (__float_as_uint(l0) >> 16) | (__float_as_uint(l1) & 0xFFFF0000u);
    }
    hi = H.v; lo = L.v;
}

// B-frags for a 64x64 row-major weight: whi/wlo[ks][g], ks=K-step (k 0..31 / 32..63),
// g=channel group (cols g*16..+15). Lane: k=(lane>>4)*8+j, n=lane&15.
__device__ __forceinline__ void load_wfrags(const float* __restrict__ W, int lane,
                                            s8 whi[2][4], s8 wlo[2][4]) {
    int q = lane >> 4, c = lane & 15;
    #pragma unroll
    for (int ks = 0; ks < 2; ++ks)
        #pragma unroll
        for (int g = 0; g < 4; ++g) {
            float t[8];
            #pragma unroll
            for (int j = 0; j < 8; ++j)
                t[j] = W[(ks*32 + q*8 + j) * 64 + g*16 + c];
            split8(t, whi[ks][g], wlo[ks][g]);
        }
}

// C[n,:] = embed[Z[n],:]
__global__ void k_init_C(const int* __restrict__ Z, const float* __restrict__ embed,
                         float* __restrict__ C) {
    int i = blockIdx.x * blockDim.x + threadIdx.x;
    if (i >= N_NODES * BASIS) return;
    int n = i >> 6, c = i & 63;
    C[i] = embed[Z[n] * BASIS + c];
}

// out[r,:] = in[r,:] @ W(64x64) + b  via split-bf16 MFMA; wave per 16-row chunk.
__global__ __launch_bounds__(256) void k_gemm64(const float* __restrict__ in,
        const float* __restrict__ W, const float* __restrict__ b,
        float* __restrict__ out, int rows) {
    int lane = threadIdx.x & 63, wv = threadIdx.x >> 6;
    int q = lane >> 4, c = lane & 15;
    s8 whi[2][4], wlo[2][4];
    load_wfrags(W, lane, whi, wlo);
    float bias[4];
    #pragma unroll
    for (int g = 0; g < 4; ++g) bias[g] = b[g*16 + c];
    int chunks = (rows + 15) >> 4;
    int wave = blockIdx.x * 4 + wv, nw = gridDim.x * 4;
    for (int ch = wave; ch < chunks; ch += nw) {
        int base = ch << 4;
        int row = base + c;                 // A-load row for this lane (m = lane&15)
        bool valid = row < rows;
        const float4* ip = (const float4*)(in + (size_t)(valid ? row : 0) * 64);
        s8 ahi[2], alo[2];
        #pragma unroll
        for (int ks = 0; ks < 2; ++ks) {
            float4 a0 = ip[ks*8 + q*2 + 0];
            float4 a1 = ip[ks*8 + q*2 + 1];
            float xs[8] = {a0.x,a0.y,a0.z,a0.w, a1.x,a1.y,a1.z,a1.w};
            if (!valid) {
                #pragma unroll
                for (int j = 0; j < 8; ++j) xs[j] = 0.0f;
            }
            split8(xs, ahi[ks], alo[ks]);
        }
        f4 acc[4];
        #pragma unroll
        for (int g = 0; g < 4; ++g) acc[g] = splat4(bias[g]);
        #pragma unroll
        for (int ks = 0; ks < 2; ++ks)
            #pragma unroll
            for (int g = 0; g < 4; ++g) {
                acc[g] = MFMA16(ahi[ks], whi[ks][g], acc[g]);
                acc[g] = MFMA16(ahi[ks], wlo[ks][g], acc[g]);
                acc[g] = MFMA16(alo[ks], whi[ks][g], acc[g]);
            }
        #pragma unroll
        for (int g = 0; g < 4; ++g)
            #pragma unroll
            for (int r = 0; r < 4; ++r) {
                int ro = base + q*4 + r;    // D row = (lane>>4)*4 + reg
                if (ro < rows) out[(size_t)ro * 64 + g*16 + c] = acc[g][r];
            }
    }
}

// ---- CSR build ----
__global__ void k_hist(const int* __restrict__ dst, int* __restrict__ deg) {
    int e = blockIdx.x * blockDim.x + threadIdx.x;
    if (e < N_EDGES) atomicAdd(&deg[dst[e]], 1);
}

// single-block shuffle-based scan (2 syncthreads per 1024-chunk)
__global__ void k_scan(const int* __restrict__ deg, int* __restrict__ off,
                       int* __restrict__ cursor) {
    __shared__ int wsum[16];
    __shared__ int run_s;
    int t = threadIdx.x, lane = t & 63, w = t >> 6;
    if (t == 0) run_s = 0;
    __syncthreads();
    for (int base = 0; base < N_NODES; base += 1024) {
        int i = base + t;
        int v = (i < N_NODES) ? deg[i] : 0;
        int s = v;
        #pragma unroll
        for (int ofs = 1; ofs < 64; ofs <<= 1) {
            int tmp = __shfl_up(s, ofs, 64);
            if (lane >= ofs) s += tmp;
        }
        if (lane == 63) wsum[w] = s;
        __syncthreads();
        if (w == 0) {
            int x = (lane < 16) ? wsum[lane] : 0;
            #pragma unroll
            for (int ofs = 1; ofs < 16; ofs <<= 1) {
                int tmp = __shfl_up(x, ofs, 64);
                if (lane >= ofs) x += tmp;
            }
            if (lane < 16) wsum[lane] = x;   // inclusive wave sums
        }
        __syncthreads();
        int run = run_s;
        int wex = (w == 0) ? 0 : wsum[w - 1];
        int incl = run + wex + s;
        if (i < N_NODES) { off[i] = incl - v; cursor[i] = incl - v; }
        __syncthreads();
        if (t == 1023) run_s = incl;
        __syncthreads();
    }
    if (t == 0) off[N_NODES] = run_s;
}

__global__ void k_fill(const int* __restrict__ dst, int* __restrict__ cursor,
                       int* __restrict__ eid) {
    int e = blockIdx.x * blockDim.x + threadIdx.x;
    if (e < N_EDGES) {
        int p = atomicAdd(&cursor[dst[e]], 1);
        eid[p] = e;
    }
}

// ---- fused message+aggregate, MFMA edition: wave per node, 16-edge chunks ----
__global__ __launch_bounds__(256) void k_mp_mfma(const float* __restrict__ CF,
        const float* __restrict__ DF, const float* __restrict__ fcW,
        const int* __restrict__ src, const int* __restrict__ off,
        const int* __restrict__ eid, float* __restrict__ C) {
    int lane = threadIdx.x & 63, wv = threadIdx.x >> 6;
    int q = lane >> 4, c = lane & 15;
    s8 whi[2][4], wlo[2][4];
    load_wfrags(fcW, lane, whi, wlo);
    int wave = blockIdx.x * 4 + wv, nw = gridDim.x * 4;
    for (int n = wave; n < N_NODES; n += nw) {
        int beg = off[n], end = off[n + 1];
        float acc0 = 0.f, acc1 = 0.f, acc2 = 0.f, acc3 = 0.f;
        #pragma unroll 1
        for (int base = beg; base < end; base += 16) {
            int cnt = end - base;
            bool valid = c < cnt;               // this lane's A row m = c
            int idx = base + (valid ? c : 0);
            int e = eid[idx];
            int s = src[e];
            const float4* cfp = (const float4*)(CF + (size_t)s * 64);
            const float4* dfp = (const float4*)(DF + (size_t)e * 64);
            s8 ahi[2], alo[2];
            #pragma unroll
            for (int ks = 0; ks < 2; ++ks) {
                float4 c0 = cfp[ks*8 + q*2 + 0];
                float4 c1 = cfp[ks*8 + q*2 + 1];
                float4 d0 = dfp[ks*8 + q*2 + 0];
                float4 d1 = dfp[ks*8 + q*2 + 1];
                float xs[8] = {c0.x*d0.x, c0.y*d0.y, c0.z*d0.z, c0.w*d0.w,
                               c1.x*d1.x, c1.y*d1.y, c1.z*d1.z, c1.w*d1.w};
                if (!valid) {
                    #pragma unroll
                    for (int j = 0; j < 8; ++j) xs[j] = 0.0f;
                }
                split8(xs, ahi[ks], alo[ks]);
            }
            f4 d[4];
            #pragma unroll
            for (int g = 0; g < 4; ++g) d[g] = splat4(0.0f);
            #pragma unroll
            for (int ks = 0; ks < 2; ++ks)
                #pragma unroll
                for (int g = 0; g < 4; ++g) {
                    d[g] = MFMA16(ahi[ks], whi[ks][g], d[g]);
                    d[g] = MFMA16(ahi[ks], wlo[ks][g], d[g]);
                    d[g] = MFMA16(alo[ks], whi[ks][g], d[g]);
                }
            // tail rows had zero A -> d=0 -> tanh(0)=0: safe to sum all 4 regs
            acc0 += fast_tanh(d[0][0]) + fast_tanh(d[0][1]) + fast_tanh(d[0][2]) + fast_tanh(d[0][3]);
            acc1 += fast_tanh(d[1][0]) + fast_tanh(d[1][1]) + fast_tanh(d[1][2]) + fast_tanh(d[1][3]);
            acc2 += fast_tanh(d[2][0]) + fast_tanh(d[2][1]) + fast_tanh(d[2][2]) + fast_tanh(d[2][3]);
            acc3 += fast_tanh(d[3][0]) + fast_tanh(d[3][1]) + fast_tanh(d[3][2]) + fast_tanh(d[3][3]);
        }
        // reduce across the 4 lane-quads (edge-row subsets)
        acc0 += __shfl_xor(acc0, 16, 64); acc0 += __shfl_xor(acc0, 32, 64);
        acc1 += __shfl_xor(acc1, 16, 64); acc1 += __shfl_xor(acc1, 32, 64);
        acc2 += __shfl_xor(acc2, 16, 64); acc2 += __shfl_xor(acc2, 32, 64);
        acc3 += __shfl_xor(acc3, 16, 64); acc3 += __shfl_xor(acc3, 32, 64);
        float v = (q == 0) ? acc0 : (q == 1) ? acc1 : (q == 2) ? acc2 : acc3;
        C[(size_t)n * 64 + lane] += v;      // channel = q*16 + c = lane
    }
}

// ---- fallback edge kernel (only if ws too small; never expected) ----
__global__ __launch_bounds__(256) void k_edge_fb(const float* __restrict__ CF,
        const float* __restrict__ ea, const float* __restrict__ dfW,
        const float* __restrict__ dfb, const float* __restrict__ fcW,
        const int* __restrict__ src, const int* __restrict__ dst,
        float* __restrict__ C) {
    int e = blockIdx.x * blockDim.x + threadIdx.x;
    if (e >= N_EDGES) return;
    int s = src[e], d = dst[e];
    float dfeat[BASIS];
    #pragma unroll
    for (int c = 0; c < BASIS; ++c) dfeat[c] = dfb[c];
    const float4* ea4 = (const float4*)(ea + (size_t)e * BASIS);
    #pragma unroll
    for (int k0 = 0; k0 < 16; ++k0) {
        float4 xv = ea4[k0];
        #pragma unroll
        for (int c = 0; c < BASIS; ++c)
            dfeat[c] += xv.x * dfW[(4*k0+0)*64+c] + xv.y * dfW[(4*k0+1)*64+c]
                      + xv.z * dfW[(4*k0+2)*64+c] + xv.w * dfW[(4*k0+3)*64+c];
    }
    const float4* cf4 = (const float4*)(CF + (size_t)s * BASIS);
    float acc[BASIS];
    #pragma unroll
    for (int c = 0; c < BASIS; ++c) acc[c] = 0.0f;
    #pragma unroll
    for (int k0 = 0; k0 < 16; ++k0) {
        float4 a = cf4[k0];
        float x0 = a.x * dfeat[4*k0+0], x1 = a.y * dfeat[4*k0+1];
        float x2 = a.z * dfeat[4*k0+2], x3 = a.w * dfeat[4*k0+3];
        #pragma unroll
        for (int c = 0; c < BASIS; ++c)
            acc[c] += x0 * fcW[(4*k0+0)*64+c] + x1 * fcW[(4*k0+1)*64+c]
                    + x2 * fcW[(4*k0+2)*64+c] + x3 * fcW[(4*k0+3)*64+c];
    }
    float* crow = C + (size_t)d * BASIS;
    #pragma unroll
    for (int c = 0; c < BASIS; ++c) atomicAdd(&crow[c], fast_tanh(acc[c]));
}

// ---- readout: wave per node, W1 in LDS ----
__global__ __launch_bounds__(256) void k_readout2(const float* __restrict__ C,
        const float* __restrict__ W1, const float* __restrict__ b1,
        const float* __restrict__ W2, const float* __restrict__ b2,
        const int* __restrict__ batch, float* __restrict__ out) {
    __shared__ float w1[BASIS * HIDDEN_RO];   // 32 KB
    __shared__ float xbuf[4][64];
    int t = threadIdx.x;
    for (int i = t; i < BASIS * HIDDEN_RO; i += 256) w1[i] = W1[i];
    __syncthreads();
    int lane = t & 63, wv = t >> 6;
    float b1a = b1[lane], b1b = b1[64 + lane];
    float4 w2a = ((const float4*)W2)[lane];
    float4 w2b = ((const float4*)W2)[64 + lane];
    int wave = blockIdx.x * 4 + wv;
    int nw   = gridDim.x * 4;
    for (int n = wave; n < N_NODES; n += nw) {
        float x = C[(size_t)n * 64 + lane];
        xbuf[wv][lane] = x;
        __builtin_amdgcn_wave_barrier();
        const float4* xb = (const float4*)xbuf[wv];
        float sa = b1a, sb = b1b;
        #pragma unroll
        for (int k4 = 0; k4 < 16; ++k4) {
            float4 xv = xb[k4];
            const float* r0 = &w1[(4*k4 + 0) * HIDDEN_RO];
            const float* r1 = &w1[(4*k4 + 1) * HIDDEN_RO];
            const float* r2 = &w1[(4*k4 + 2) * HIDDEN_RO];
            const float* r3 = &w1[(4*k4 + 3) * HIDDEN_RO];
            sa += xv.x * r0[lane]      + xv.y * r1[lane]
                + xv.z * r2[lane]      + xv.w * r3[lane];
            sb += xv.x * r0[64 + lane] + xv.y * r1[64 + lane]
                + xv.z * r2[64 + lane] + xv.w * r3[64 + lane];
        }
        float ha = fast_tanh(sa), hb = fast_tanh(sb);
        float v0 = ha * w2a.x + hb * w2b.x;
        float v1 = ha * w2a.y + hb * w2b.y;
        float v2 = ha * w2a.z + hb * w2b.z;
        float v3 = ha * w2a.w + hb * w2b.w;
        #pragma unroll
        for (int ofs = 32; ofs >= 1; ofs >>= 1) {
            v0 += __shfl_down(v0, ofs, 64);
            v1 += __shfl_down(v1, ofs, 64);
            v2 += __shfl_down(v2, ofs, 64);
            v3 += __shfl_down(v3, ofs, 64);
        }
        if (lane == 0) {
            int g = batch[n];
            atomicAdd(&out[(size_t)g * 4 + 0], v0);
            atomicAdd(&out[(size_t)g * 4 + 1], v1);
            atomicAdd(&out[(size_t)g * 4 + 2], v2);
            atomicAdd(&out[(size_t)g * 4 + 3], v3);
        }
        __builtin_amdgcn_wave_barrier();
    }
}

extern "C" void kernel_launch(void* const* d_in, const int* in_sizes, int n_in,
                              void* d_out, int out_size, void* d_ws, size_t ws_size,
                              hipStream_t stream) {
    // Z, edge_index, edge_attr, batch, embed, cfW, cfb, dfW, dfb, fcW, W1, b1, W2, b2
    const int*   Z     = (const int*)d_in[0];
    const int*   ei    = (const int*)d_in[1];
    const float* ea    = (const float*)d_in[2];
    const int*   batch = (const int*)d_in[3];
    const float* embed = (const float*)d_in[4];
    const float* cfW   = (const float*)d_in[5];
    const float* cfb   = (const float*)d_in[6];
    const float* dfW   = (const float*)d_in[7];
    const float* dfb   = (const float*)d_in[8];
    const float* fcW   = (const float*)d_in[9];
    const float* W1    = (const float*)d_in[10];
    const float* b1    = (const float*)d_in[11];
    const float* W2    = (const float*)d_in[12];
    const float* b2    = (const float*)d_in[13];
    const int* src = ei;
    const int* dst = ei + N_EDGES;
    float* out = (float*)d_out;

    const size_t bC = (size_t)N_NODES * BASIS * sizeof(float);   // 12.8 MB
    const size_t bE = (size_t)N_EDGES * sizeof(int);             // 3.2 MB
    const size_t bO = (size_t)(N_NODES + 1) * sizeof(int);
    char* p = (char*)d_ws;
    float* C      = (float*)p;  p += bC;
    float* CF     = (float*)p;  p += bC;
    int*   eid    = (int*)p;    p += bE;
    int*   deg    = (int*)p;    p += bO;
    int*   off    = (int*)p;    p += bO;
    int*   cursor = (int*)p;    p += bO;
    float* DF     = (float*)p;
    const size_t need = (size_t)(p - (char*)d_ws) + (size_t)N_EDGES * BASIS * sizeof(float);
    const bool full = ws_size >= need;   // 234.2 MB — held in rounds 1 & 2

    hipMemsetAsync(d_out, 0, (size_t)out_size * sizeof(float), stream);
    k_init_C<<<(N_NODES * BASIS + 255) / 256, 256, 0, stream>>>(Z, embed, C);

    if (full) {
        hipMemsetAsync(deg, 0, bO, stream);
        k_hist<<<(N_EDGES + 255) / 256, 256, 0, stream>>>(dst, deg);
        k_scan<<<1, 1024, 0, stream>>>(deg, off, cursor);
        k_fill<<<(N_EDGES + 255) / 256, 256, 0, stream>>>(dst, cursor, eid);
        k_gemm64<<<4096, 256, 0, stream>>>(ea, dfW, dfb, DF, N_EDGES);
        for (int t = 0; t < T_ITERS; ++t) {
            k_gemm64<<<800, 256, 0, stream>>>(C, cfW, cfb, CF, N_NODES);
            k_mp_mfma<<<2048, 256, 0, stream>>>(CF, DF, fcW, src, off, eid, C);
        }
    } else {
        for (int t = 0; t < T_ITERS; ++t) {
            k_gemm64<<<800, 256, 0, stream>>>(C, cfW, cfb, CF, N_NODES);
            k_edge_fb<<<(N_EDGES + 255) / 256, 256, 0, stream>>>(CF, ea, dfW, dfb, fcW, src, dst, C);
        }
    }

    k_readout2<<<512, 256, 0, stream>>>(C, W1, b1, W2, b2, batch, out);
}